// Round 16
// baseline (1450.669 us; speedup 1.0000x reference)
//
#include <hip/hip_runtime.h>
#include <math.h>

#define L 200
#define H 128
#define HD 64
#define NB 2
#define BTOT 2048
#define HH (H * H)
#define MTOT (BTOT * L)
#define XSS 136   // LDS row stride in shorts (272B, 16B-aligned)

typedef short bf16x8 __attribute__((ext_vector_type(8)));
typedef float f32x4 __attribute__((ext_vector_type(4)));
typedef unsigned short u16;

#define MFMA16 __builtin_amdgcn_mfma_f32_16x16x32_bf16

// ---------- helpers ----------
__device__ __forceinline__ u16 f2bf(float f) {
    unsigned u = __builtin_bit_cast(unsigned, f);
    u = u + 0x7fffu + ((u >> 16) & 1u);
    return (u16)(u >> 16);
}
__device__ __forceinline__ float bf2f(u16 s) {
    return __builtin_bit_cast(float, ((unsigned)s) << 16);
}
__device__ __forceinline__ bf16x8 pack8(float4 a, float4 b, float sc) {
    bf16x8 r;
    r[0] = (short)f2bf(a.x * sc); r[1] = (short)f2bf(a.y * sc);
    r[2] = (short)f2bf(a.z * sc); r[3] = (short)f2bf(a.w * sc);
    r[4] = (short)f2bf(b.x * sc); r[5] = (short)f2bf(b.y * sc);
    r[6] = (short)f2bf(b.z * sc); r[7] = (short)f2bf(b.w * sc);
    return r;
}

// ---------- weight f32 -> bf16 ----------
__global__ __launch_bounds__(256) void cvt_kernel(const float* __restrict__ src,
                                                  u16* __restrict__ dst, int n8) {
    int i = blockIdx.x * 256 + threadIdx.x;
    if (i >= n8) return;
    float4 a0 = ((const float4*)src)[i * 2];
    float4 a1 = ((const float4*)src)[i * 2 + 1];
    ((bf16x8*)dst)[i] = pack8(a0, a1, 1.0f);
}

// ---------- embedding (bf16 out) ----------
__global__ __launch_bounds__(256) void embed_kernel(const int* __restrict__ ids,
                                                    const float4* __restrict__ item,
                                                    const float4* __restrict__ post,
                                                    u16* __restrict__ X, int M) {
    int idx = blockIdx.x * 256 + threadIdx.x;
    if (idx >= M * 16) return;
    int r = idx >> 4, c8 = idx & 15;
    int id = ids[r];
    int l = r % L;
    int p = (id != 0) ? (l + 1) : 0;
    float4 a0 = item[(size_t)id * 32 + c8 * 2];
    float4 a1 = item[(size_t)id * 32 + c8 * 2 + 1];
    float4 p0 = post[(size_t)p * 32 + c8 * 2];
    float4 p1 = post[(size_t)p * 32 + c8 * 2 + 1];
    const float sc = 11.313708498984761f;  // sqrt(128)
    float4 o0 = make_float4(a0.x * sc + p0.x, a0.y * sc + p0.y, a0.z * sc + p0.z, a0.w * sc + p0.w);
    float4 o1 = make_float4(a1.x * sc + p1.x, a1.y * sc + p1.y, a1.z * sc + p1.z, a1.w * sc + p1.w);
    *(bf16x8*)&X[(size_t)r * 128 + c8 * 8] = pack8(o0, o1, 1.0f);
}

// ---------- fused QKV (bf16 in/out, Q pre-scaled 0.125) [round-4 verbatim] ----------
__global__ __launch_bounds__(256) void qkv_kernel(const u16* __restrict__ X,
        const u16* __restrict__ wq, const u16* __restrict__ wk, const u16* __restrict__ wv,
        const float* __restrict__ qb, const float* __restrict__ kb, const float* __restrict__ vb,
        u16* __restrict__ Qo, u16* __restrict__ Ko, u16* __restrict__ Vo, int M) {
    __shared__ u16 Xs[128 * XSS];
    __shared__ u16 Ot[4][16 * XSS];
    int tid = threadIdx.x, w = tid >> 6, lane = tid & 63, g = lane >> 4, l15 = lane & 15;
    int row0 = blockIdx.x * 128;
#pragma unroll
    for (int it = 0; it < 8; ++it) {
        int idx = it * 256 + tid;
        int r = idx >> 4, c8 = idx & 15;
        size_t gr = (size_t)min(row0 + r, M - 1);
        *(bf16x8*)&Xs[r * XSS + c8 * 8] = *(const bf16x8*)(X + gr * 128 + c8 * 8);
    }
    __syncthreads();

    int arow = w * 32 + l15;
    int ko = g * 8;

#pragma unroll
    for (int p = 0; p < 3; ++p) {
        const u16* Wp = p == 0 ? wq : (p == 1 ? wk : wv);
        const float* bp = p == 0 ? qb : (p == 1 ? kb : vb);
        u16* Op = p == 0 ? Qo : (p == 1 ? Ko : Vo);
        const float scale = p == 0 ? 0.125f : 1.0f;

        f32x4 acc[2][8];
#pragma unroll
        for (int nt = 0; nt < 8; ++nt) {
            float bv = bp[nt * 16 + l15];
            acc[0][nt] = (f32x4){bv, bv, bv, bv};
            acc[1][nt] = (f32x4){bv, bv, bv, bv};
        }
#pragma unroll
        for (int kc = 0; kc < 4; ++kc) {
            bf16x8 a0 = *(const bf16x8*)&Xs[arow * XSS + kc * 32 + ko];
            bf16x8 a1 = *(const bf16x8*)&Xs[(arow + 16) * XSS + kc * 32 + ko];
#pragma unroll
            for (int nt = 0; nt < 8; ++nt) {
                bf16x8 b = *(const bf16x8*)(Wp + ((size_t)(nt * 16 + l15) << 7) + kc * 32 + ko);
                acc[0][nt] = MFMA16(a0, b, acc[0][nt], 0, 0, 0);
                acc[1][nt] = MFMA16(a1, b, acc[1][nt], 0, 0, 0);
            }
        }
#pragma unroll
        for (int mt = 0; mt < 2; ++mt) {
#pragma unroll
            for (int r = 0; r < 4; ++r) {
                int ml = g * 4 + r;
#pragma unroll
                for (int nt = 0; nt < 8; ++nt)
                    Ot[w][ml * XSS + nt * 16 + l15] = f2bf(acc[mt][nt][r] * scale);
            }
            asm volatile("s_waitcnt lgkmcnt(0)" ::: "memory");
#pragma unroll
            for (int j = 0; j < 4; ++j) {
                int chunk = j * 64 + lane;
                int rr = chunk >> 4, c16 = chunk & 15;
                bf16x8 v = *(const bf16x8*)&Ot[w][rr * XSS + c16 * 8];
                int grow = row0 + w * 32 + mt * 16 + rr;
                if (grow < M) *(bf16x8*)(Op + (size_t)grow * 128 + c16 * 8) = v;
            }
            asm volatile("s_waitcnt lgkmcnt(0)" ::: "memory");
        }
    }
}

// ---------- fused O-proj + residual + LN1 + FFN1 [round-4 verbatim] ----------
__global__ __launch_bounds__(256) void oproj_ffn1_kernel(const u16* __restrict__ A,
        const u16* __restrict__ Wo, const float* __restrict__ ob,
        const u16* __restrict__ Xres, const float* __restrict__ gma, const float* __restrict__ bta,
        const u16* __restrict__ W1, const float* __restrict__ b1f,
        u16* __restrict__ Xout, u16* __restrict__ F1, int M) {
    __shared__ u16 Xs[128 * XSS];
    __shared__ u16 Ot[4][16 * XSS];
    int tid = threadIdx.x, w = tid >> 6, lane = tid & 63, g = lane >> 4, l15 = lane & 15;
    int row0 = blockIdx.x * 128;
    int rw = row0 + w * 32;
    size_t ar0 = (size_t)min(rw + l15, M - 1) * 128;
    size_t ar1 = (size_t)min(rw + 16 + l15, M - 1) * 128;
    int ko = g * 8;

    f32x4 acc[2][8];
#pragma unroll
    for (int nt = 0; nt < 8; ++nt) {
        float bv = ob[nt * 16 + l15];
        acc[0][nt] = (f32x4){bv, bv, bv, bv};
        acc[1][nt] = (f32x4){bv, bv, bv, bv};
    }
#pragma unroll
    for (int kc = 0; kc < 4; ++kc) {
        bf16x8 a0 = *(const bf16x8*)(A + ar0 + kc * 32 + ko);
        bf16x8 a1 = *(const bf16x8*)(A + ar1 + kc * 32 + ko);
#pragma unroll
        for (int nt = 0; nt < 8; ++nt) {
            bf16x8 b = *(const bf16x8*)(Wo + ((size_t)(nt * 16 + l15) << 7) + kc * 32 + ko);
            acc[0][nt] = MFMA16(a0, b, acc[0][nt], 0, 0, 0);
            acc[1][nt] = MFMA16(a1, b, acc[1][nt], 0, 0, 0);
        }
    }
    float gg[8], bb[8];
#pragma unroll
    for (int nt = 0; nt < 8; ++nt) { gg[nt] = gma[nt * 16 + l15]; bb[nt] = bta[nt * 16 + l15]; }
#pragma unroll
    for (int mt = 0; mt < 2; ++mt) {
#pragma unroll
        for (int r = 0; r < 4; ++r) {
            int rowl = w * 32 + mt * 16 + g * 4 + r;
            size_t rb = (size_t)min(row0 + rowl, M - 1) * 128;
            float v[8];
            float s = 0.f;
#pragma unroll
            for (int nt = 0; nt < 8; ++nt) { v[nt] = acc[mt][nt][r] + bf2f(Xres[rb + nt * 16 + l15]); s += v[nt]; }
            s += __shfl_xor(s, 1); s += __shfl_xor(s, 2); s += __shfl_xor(s, 4); s += __shfl_xor(s, 8);
            float mean = s * 0.0078125f;
            float s2 = 0.f;
#pragma unroll
            for (int nt = 0; nt < 8; ++nt) { float d = v[nt] - mean; s2 += d * d; }
            s2 += __shfl_xor(s2, 1); s2 += __shfl_xor(s2, 2); s2 += __shfl_xor(s2, 4); s2 += __shfl_xor(s2, 8);
            float inv = rsqrtf(s2 * 0.0078125f + 1e-8f);
#pragma unroll
            for (int nt = 0; nt < 8; ++nt)
                Xs[rowl * XSS + nt * 16 + l15] = f2bf((v[nt] - mean) * inv * gg[nt] + bb[nt]);
        }
    }
    __syncthreads();

#pragma unroll
    for (int it = 0; it < 8; ++it) {
        int idx = it * 256 + tid;
        int r = idx >> 4, c8 = idx & 15;
        int grow = row0 + r;
        if (grow < M)
            *(bf16x8*)(Xout + (size_t)grow * 128 + c8 * 8) = *(const bf16x8*)&Xs[r * XSS + c8 * 8];
    }

    int arow = w * 32 + l15;
    f32x4 acc2[2][8];
#pragma unroll
    for (int nt = 0; nt < 8; ++nt) {
        float bv = b1f[nt * 16 + l15];
        acc2[0][nt] = (f32x4){bv, bv, bv, bv};
        acc2[1][nt] = (f32x4){bv, bv, bv, bv};
    }
#pragma unroll
    for (int kc = 0; kc < 4; ++kc) {
        bf16x8 a0 = *(const bf16x8*)&Xs[arow * XSS + kc * 32 + ko];
        bf16x8 a1 = *(const bf16x8*)&Xs[(arow + 16) * XSS + kc * 32 + ko];
#pragma unroll
        for (int nt = 0; nt < 8; ++nt) {
            bf16x8 b = *(const bf16x8*)(W1 + ((size_t)(nt * 16 + l15) << 7) + kc * 32 + ko);
            acc2[0][nt] = MFMA16(a0, b, acc2[0][nt], 0, 0, 0);
            acc2[1][nt] = MFMA16(a1, b, acc2[1][nt], 0, 0, 0);
        }
    }
#pragma unroll
    for (int mt = 0; mt < 2; ++mt) {
#pragma unroll
        for (int r = 0; r < 4; ++r) {
            int ml = g * 4 + r;
#pragma unroll
            for (int nt = 0; nt < 8; ++nt)
                Ot[w][ml * XSS + nt * 16 + l15] = f2bf(fmaxf(acc2[mt][nt][r], 0.f));
        }
        asm volatile("s_waitcnt lgkmcnt(0)" ::: "memory");
#pragma unroll
        for (int j = 0; j < 4; ++j) {
            int chunk = j * 64 + lane;
            int rr = chunk >> 4, c16 = chunk & 15;
            bf16x8 v = *(const bf16x8*)&Ot[w][rr * XSS + c16 * 8];
            int grow = row0 + w * 32 + mt * 16 + rr;
            if (grow < M) *(bf16x8*)(F1 + (size_t)grow * 128 + c16 * 8) = v;
        }
        asm volatile("s_waitcnt lgkmcnt(0)" ::: "memory");
    }
}

// ---------- FFN2 + residual + LN2 (+ final LN + logits when fin) [round-4 verbatim] ----------
__global__ __launch_bounds__(256) void ffn2_ln_kernel(const u16* __restrict__ A,
        const u16* __restrict__ W2, const float* __restrict__ bias,
        const u16* __restrict__ Xres, const float* __restrict__ gma, const float* __restrict__ bta,
        const float* __restrict__ gf, const float* __restrict__ bff, int fin,
        u16* __restrict__ Xout, const float* __restrict__ item,
        const int* __restrict__ pid, const int* __restrict__ nid,
        float* __restrict__ out, int gofs, int M) {
    __shared__ u16 Ot[4][16 * XSS];
    int tid = threadIdx.x, w = tid >> 6, lane = tid & 63, g = lane >> 4, l15 = lane & 15;
    int row0 = blockIdx.x * 128;
    int rw = row0 + w * 32;
    size_t ar0 = (size_t)min(rw + l15, M - 1) * 128;
    size_t ar1 = (size_t)min(rw + 16 + l15, M - 1) * 128;
    int ko = g * 8;

    f32x4 acc[2][8];
#pragma unroll
    for (int nt = 0; nt < 8; ++nt) {
        float bv = bias[nt * 16 + l15];
        acc[0][nt] = (f32x4){bv, bv, bv, bv};
        acc[1][nt] = (f32x4){bv, bv, bv, bv};
    }
#pragma unroll
    for (int kc = 0; kc < 4; ++kc) {
        bf16x8 a0 = *(const bf16x8*)(A + ar0 + kc * 32 + ko);
        bf16x8 a1 = *(const bf16x8*)(A + ar1 + kc * 32 + ko);
#pragma unroll
        for (int nt = 0; nt < 8; ++nt) {
            bf16x8 b = *(const bf16x8*)(W2 + ((size_t)(nt * 16 + l15) << 7) + kc * 32 + ko);
            acc[0][nt] = MFMA16(a0, b, acc[0][nt], 0, 0, 0);
            acc[1][nt] = MFMA16(a1, b, acc[1][nt], 0, 0, 0);
        }
    }
    float gg[8], bb[8], gg2[8], bb2[8];
#pragma unroll
    for (int nt = 0; nt < 8; ++nt) {
        gg[nt] = gma[nt * 16 + l15]; bb[nt] = bta[nt * 16 + l15];
        gg2[nt] = gf[nt * 16 + l15]; bb2[nt] = bff[nt * 16 + l15];
    }
#pragma unroll
    for (int mt = 0; mt < 2; ++mt) {
#pragma unroll
        for (int r = 0; r < 4; ++r) {
            int row = row0 + w * 32 + mt * 16 + g * 4 + r;
            size_t rb = (size_t)min(row, M - 1) * 128;
            float v[8];
            float s = 0.f;
#pragma unroll
            for (int nt = 0; nt < 8; ++nt) { v[nt] = acc[mt][nt][r] + bf2f(Xres[rb + nt * 16 + l15]); s += v[nt]; }
            s += __shfl_xor(s, 1); s += __shfl_xor(s, 2); s += __shfl_xor(s, 4); s += __shfl_xor(s, 8);
            float mean = s * 0.0078125f;
            float s2 = 0.f;
#pragma unroll
            for (int nt = 0; nt < 8; ++nt) { float d = v[nt] - mean; s2 += d * d; }
            s2 += __shfl_xor(s2, 1); s2 += __shfl_xor(s2, 2); s2 += __shfl_xor(s2, 4); s2 += __shfl_xor(s2, 8);
            float inv = rsqrtf(s2 * 0.0078125f + 1e-8f);
#pragma unroll
            for (int nt = 0; nt < 8; ++nt) v[nt] = (v[nt] - mean) * inv * gg[nt] + bb[nt];
            if (fin) {
                float t = 0.f;
#pragma unroll
                for (int nt = 0; nt < 8; ++nt) t += v[nt];
                t += __shfl_xor(t, 1); t += __shfl_xor(t, 2); t += __shfl_xor(t, 4); t += __shfl_xor(t, 8);
                float mean2 = t * 0.0078125f;
                float t2 = 0.f;
#pragma unroll
                for (int nt = 0; nt < 8; ++nt) { float d = v[nt] - mean2; t2 += d * d; }
                t2 += __shfl_xor(t2, 1); t2 += __shfl_xor(t2, 2); t2 += __shfl_xor(t2, 4); t2 += __shfl_xor(t2, 8);
                float inv2 = rsqrtf(t2 * 0.0078125f + 1e-8f);
#pragma unroll
                for (int nt = 0; nt < 8; ++nt) v[nt] = (v[nt] - mean2) * inv2 * gg2[nt] + bb2[nt];
                int gr = gofs + row;
                const float* prow = item + (size_t)pid[gr] * 128;
                const float* nrow = item + (size_t)nid[gr] * 128;
                float sp = 0.f, sn = 0.f;
#pragma unroll
                for (int nt = 0; nt < 8; ++nt) {
                    sp += v[nt] * prow[nt * 16 + l15];
                    sn += v[nt] * nrow[nt * 16 + l15];
                }
                sp += __shfl_xor(sp, 1); sp += __shfl_xor(sp, 2); sp += __shfl_xor(sp, 4); sp += __shfl_xor(sp, 8);
                sn += __shfl_xor(sn, 1); sn += __shfl_xor(sn, 2); sn += __shfl_xor(sn, 4); sn += __shfl_xor(sn, 8);
                if (l15 == 0 && row < M) {
                    out[gr] = sp;
                    out[(size_t)BTOT * L + gr] = sn;
                }
            } else {
                int ml = g * 4 + r;
#pragma unroll
                for (int nt = 0; nt < 8; ++nt)
                    Ot[w][ml * XSS + nt * 16 + l15] = f2bf(v[nt]);
            }
        }
        if (!fin) {
            asm volatile("s_waitcnt lgkmcnt(0)" ::: "memory");
#pragma unroll
            for (int j = 0; j < 4; ++j) {
                int chunk = j * 64 + lane;
                int rr = chunk >> 4, c16 = chunk & 15;
                bf16x8 v = *(const bf16x8*)&Ot[w][rr * XSS + c16 * 8];
                int grow = row0 + w * 32 + mt * 16 + rr;
                if (grow < M) *(bf16x8*)(Xout + (size_t)grow * 128 + c16 * 8) = v;
            }
            asm volatile("s_waitcnt lgkmcnt(0)" ::: "memory");
        }
    }
}

// ---------- bf16 MFMA flash attention: per-tile outer loop, direct O stores ----------
// Same math as round-4 attn; q-tiles are independent, so processing them
// sequentially shrinks live state (~132 -> ~100 VGPR) for +1 block/CU.
__global__ __launch_bounds__(256, 2) void attn_mfma_kernel(u16* __restrict__ Q,
                                                           const u16* __restrict__ K,
                                                           const u16* __restrict__ V) {
    __shared__ u16 lds_s[64 * 264];
    int b = blockIdx.x >> 1;
    int h = blockIdx.x & 1;
    int tid = threadIdx.x;
    int w = tid >> 6;
    int lane = tid & 63;
    int g = lane >> 4;
    int l15 = lane & 15;

    const u16* Kb = K + ((size_t)b * L) * H + h * HD;
    const u16* Vb = V + ((size_t)b * L) * H + h * HD;
    u16* Qb = Q + ((size_t)b * L) * H + h * HD;

    {
        int d = tid & 63;
        int kq = tid >> 6;
#pragma unroll 8
        for (int it = 0; it < 64; ++it) {
            int k = it * 4 + kq;
            lds_s[d * 264 + k] = Vb[(size_t)min(k, L - 1) * H + d];
        }
    }
    __syncthreads();

    int rp = 8 * (l15 >> 2) + (l15 & 3);
    const f32x4 czero = {0.f, 0.f, 0.f, 0.f};

    for (int nt = 0; nt < 4; ++nt) {
        int q = nt * 64 + w * 16 + l15;
        const u16* qsrc = Qb + (size_t)min(q, L - 1) * H;
        bf16x8 qf0 = *(const bf16x8*)(qsrc + g * 8);
        bf16x8 qf1 = *(const bf16x8*)(qsrc + 32 + g * 8);

        f32x4 o[4];
#pragma unroll
        for (int md = 0; md < 4; ++md) o[md] = czero;
        float mr = -1e30f, lr = 0.f;

        for (int kc = 0; kc <= nt; ++kc) {
            int kbase = kc * 64;
            f32x4 c[4];
#pragma unroll
            for (int mt = 0; mt < 4; ++mt) {
                int krow = kbase + (mt >> 1) * 32 + (mt & 1) * 4 + rp;
                const u16* src = Kb + (size_t)min(krow, L - 1) * H;
                bf16x8 ka0 = *(const bf16x8*)(src + g * 8);
                bf16x8 ka1 = *(const bf16x8*)(src + 32 + g * 8);
                c[mt] = MFMA16(ka0, qf0, czero, 0, 0, 0);
                c[mt] = MFMA16(ka1, qf1, c[mt], 0, 0, 0);
            }
            float pm = -1e30f;
#pragma unroll
            for (int mt = 0; mt < 4; ++mt) {
#pragma unroll
                for (int r = 0; r < 4; ++r) {
                    int kact = kbase + 32 * (mt >> 1) + 4 * (mt & 1) + 8 * g + r;
                    float s = (kact <= q) ? c[mt][r] : -1e30f;
                    c[mt][r] = s;
                    pm = fmaxf(pm, s);
                }
            }
            pm = fmaxf(pm, __shfl_xor(pm, 16));
            pm = fmaxf(pm, __shfl_xor(pm, 32));
            float mnew = fmaxf(mr, pm);
            float sf = __expf(mr - mnew);
            mr = mnew;
            float ps = 0.f;
#pragma unroll
            for (int mt = 0; mt < 4; ++mt) {
#pragma unroll
                for (int r = 0; r < 4; ++r) {
                    float p = __expf(c[mt][r] - mnew);
                    c[mt][r] = p;
                    ps += p;
                }
            }
            ps += __shfl_xor(ps, 16);
            ps += __shfl_xor(ps, 32);
            lr = lr * sf + ps;
#pragma unroll
            for (int md = 0; md < 4; ++md) {
#pragma unroll
                for (int r = 0; r < 4; ++r) o[md][r] *= sf;
            }
#pragma unroll
            for (int ks = 0; ks < 2; ++ks) {
                bf16x8 pb;
#pragma unroll
                for (int j = 0; j < 8; ++j)
                    pb[j] = (short)f2bf(c[2 * ks + (j >> 2)][j & 3]);
#pragma unroll
                for (int md = 0; md < 4; ++md) {
                    const u16* vp = &lds_s[(md * 16 + l15) * 264 + kbase + ks * 32 + g * 8];
                    bf16x8 va = *(const bf16x8*)vp;
                    o[md] = MFMA16(va, pb, o[md], 0, 0, 0);
                }
            }
        }
        // direct O store (rows are lane-owned; q>=L columns fully discarded)
        if (q < L) {
            float inv = 1.0f / lr;
#pragma unroll
            for (int md = 0; md < 4; ++md) {
                unsigned p0 = (unsigned)f2bf(o[md][0] * inv) | ((unsigned)f2bf(o[md][1] * inv) << 16);
                unsigned p1 = (unsigned)f2bf(o[md][2] * inv) | ((unsigned)f2bf(o[md][3] * inv) << 16);
                uint2 uu; uu.x = p0; uu.y = p1;
                *(uint2*)(Qb + (size_t)q * H + md * 16 + g * 4) = uu;
            }
        }
    }
}

extern "C" void kernel_launch(void* const* d_in, const int* in_sizes, int n_in,
                              void* d_out, int out_size, void* d_ws, size_t ws_size,
                              hipStream_t stream) {
    const int* log_seqs = (const int*)d_in[1];
    const int* pos_seqs = (const int*)d_in[2];
    const int* neg_seqs = (const int*)d_in[3];
    const float* item = (const float*)d_in[4];
    const float* post = (const float*)d_in[5];
    const float* qw = (const float*)d_in[6];
    const float* kw = (const float*)d_in[7];
    const float* vw = (const float*)d_in[8];
    const float* ow = (const float*)d_in[9];
    const float* qb = (const float*)d_in[10];
    const float* kb = (const float*)d_in[11];
    const float* vb = (const float*)d_in[12];
    const float* ob = (const float*)d_in[13];
    const float* w1 = (const float*)d_in[14];
    const float* b1 = (const float*)d_in[15];
    const float* w2 = (const float*)d_in[16];
    const float* b2 = (const float*)d_in[17];
    const float* ln1g = (const float*)d_in[18];
    const float* ln1b = (const float*)d_in[19];
    const float* ln2g = (const float*)d_in[20];
    const float* ln2b = (const float*)d_in[21];
    const float* lnfg = (const float*)d_in[22];
    const float* lnfb = (const float*)d_in[23];
    float* out = (float*)d_out;

    // single chunk: 15 dispatches total
    int cb = BTOT;
    while (cb > 8 && (size_t)cb * L * H * 8 + 12 * HH * 2 > ws_size) cb >>= 1;
    size_t nbe = (size_t)cb * L * H;
    u16* X16 = (u16*)d_ws;
    u16* Q16 = X16 + nbe;
    u16* K16 = Q16 + nbe;
    u16* V16 = K16 + nbe;
    u16* w16 = V16 + nbe;

    const float* wsrc[6] = {qw, kw, vw, ow, w1, w2};
    int n8 = NB * HH / 8;
    for (int t = 0; t < 6; ++t)
        cvt_kernel<<<(n8 + 255) / 256, 256, 0, stream>>>(wsrc[t], w16 + (size_t)t * NB * HH, n8);

    for (int b0 = 0; b0 < BTOT; b0 += cb) {
        int M = cb * L;
        int gblk = (M + 127) / 128;
        embed_kernel<<<(M * 16 + 255) / 256, 256, 0, stream>>>(log_seqs + (size_t)b0 * L,
                                                               (const float4*)item, (const float4*)post,
                                                               X16, M);
        for (int i = 0; i < NB; ++i) {
            size_t wo = (size_t)i * HH;
            int bofs = i * H;
            qkv_kernel<<<gblk, 256, 0, stream>>>(X16,
                    w16 + 0 * NB * HH + wo, w16 + 1 * NB * HH + wo, w16 + 2 * NB * HH + wo,
                    qb + bofs, kb + bofs, vb + bofs, Q16, K16, V16, M);
            attn_mfma_kernel<<<cb * 2, 256, 0, stream>>>(Q16, K16, V16);
            oproj_ffn1_kernel<<<gblk, 256, 0, stream>>>(Q16, w16 + 3 * NB * HH + wo, ob + bofs,
                    X16, ln1g + bofs, ln1b + bofs,
                    w16 + 4 * NB * HH + wo, b1 + bofs, X16, K16, M);
            ffn2_ln_kernel<<<gblk, 256, 0, stream>>>(K16, w16 + 5 * NB * HH + wo, b2 + bofs,
                    X16, ln2g + bofs, ln2b + bofs, lnfg, lnfb, (i == NB - 1) ? 1 : 0,
                    X16, item, pos_seqs, neg_seqs, out, b0 * L, M);
        }
    }
}

// Round 17
// 1361.881 us; speedup vs baseline: 1.0652x; 1.0652x over previous
//
#include <hip/hip_runtime.h>
#include <math.h>

#define L 200
#define H 128
#define HD 64
#define NB 2
#define BTOT 2048
#define HH (H * H)
#define MTOT (BTOT * L)
#define XSS 136   // LDS row stride in shorts (272B, 16B-aligned)

typedef short bf16x8 __attribute__((ext_vector_type(8)));
typedef float f32x4 __attribute__((ext_vector_type(4)));
typedef unsigned short u16;

#define MFMA16 __builtin_amdgcn_mfma_f32_16x16x32_bf16

// ---------- helpers ----------
__device__ __forceinline__ u16 f2bf(float f) {
    unsigned u = __builtin_bit_cast(unsigned, f);
    u = u + 0x7fffu + ((u >> 16) & 1u);
    return (u16)(u >> 16);
}
__device__ __forceinline__ float bf2f(u16 s) {
    return __builtin_bit_cast(float, ((unsigned)s) << 16);
}
__device__ __forceinline__ bf16x8 pack8(float4 a, float4 b, float sc) {
    bf16x8 r;
    r[0] = (short)f2bf(a.x * sc); r[1] = (short)f2bf(a.y * sc);
    r[2] = (short)f2bf(a.z * sc); r[3] = (short)f2bf(a.w * sc);
    r[4] = (short)f2bf(b.x * sc); r[5] = (short)f2bf(b.y * sc);
    r[6] = (short)f2bf(b.z * sc); r[7] = (short)f2bf(b.w * sc);
    return r;
}

// ---------- weight f32 -> bf16 ----------
__global__ __launch_bounds__(256) void cvt_kernel(const float* __restrict__ src,
                                                  u16* __restrict__ dst, int n8) {
    int i = blockIdx.x * 256 + threadIdx.x;
    if (i >= n8) return;
    float4 a0 = ((const float4*)src)[i * 2];
    float4 a1 = ((const float4*)src)[i * 2 + 1];
    ((bf16x8*)dst)[i] = pack8(a0, a1, 1.0f);
}

// ---------- fused QKV (bf16 in/out, Q pre-scaled 0.125) ----------
// ids != nullptr (layer 0): staging computes the embedding inline
// (identical math to the old embed_kernel) and writes X16 for the residual.
__global__ __launch_bounds__(256) void qkv_kernel(const u16* __restrict__ X,
        const int* __restrict__ ids, const float4* __restrict__ item,
        const float4* __restrict__ post, u16* __restrict__ Xout,
        const u16* __restrict__ wq, const u16* __restrict__ wk, const u16* __restrict__ wv,
        const float* __restrict__ qb, const float* __restrict__ kb, const float* __restrict__ vb,
        u16* __restrict__ Qo, u16* __restrict__ Ko, u16* __restrict__ Vo, int M) {
    __shared__ u16 Xs[128 * XSS];
    __shared__ u16 Ot[4][16 * XSS];
    int tid = threadIdx.x, w = tid >> 6, lane = tid & 63, g = lane >> 4, l15 = lane & 15;
    int row0 = blockIdx.x * 128;
    if (ids) {
        const float sc = 11.313708498984761f;  // sqrt(128)
#pragma unroll
        for (int it = 0; it < 8; ++it) {
            int idx = it * 256 + tid;
            int r = idx >> 4, c8 = idx & 15;
            int grow = row0 + r;
            int id = ids[grow];
            int l = grow % L;
            int p = (id != 0) ? (l + 1) : 0;
            float4 a0 = item[(size_t)id * 32 + c8 * 2];
            float4 a1 = item[(size_t)id * 32 + c8 * 2 + 1];
            float4 p0 = post[(size_t)p * 32 + c8 * 2];
            float4 p1 = post[(size_t)p * 32 + c8 * 2 + 1];
            float4 o0 = make_float4(a0.x * sc + p0.x, a0.y * sc + p0.y, a0.z * sc + p0.z, a0.w * sc + p0.w);
            float4 o1 = make_float4(a1.x * sc + p1.x, a1.y * sc + p1.y, a1.z * sc + p1.z, a1.w * sc + p1.w);
            *(bf16x8*)&Xs[r * XSS + c8 * 8] = pack8(o0, o1, 1.0f);
        }
        __syncthreads();
        // persist the embedded residual stream (pattern proven in oproj_ffn1)
#pragma unroll
        for (int it = 0; it < 8; ++it) {
            int idx = it * 256 + tid;
            int r = idx >> 4, c8 = idx & 15;
            int grow = row0 + r;
            if (grow < M)
                *(bf16x8*)(Xout + (size_t)grow * 128 + c8 * 8) = *(const bf16x8*)&Xs[r * XSS + c8 * 8];
        }
    } else {
#pragma unroll
        for (int it = 0; it < 8; ++it) {
            int idx = it * 256 + tid;
            int r = idx >> 4, c8 = idx & 15;
            size_t gr = (size_t)min(row0 + r, M - 1);
            *(bf16x8*)&Xs[r * XSS + c8 * 8] = *(const bf16x8*)(X + gr * 128 + c8 * 8);
        }
        __syncthreads();
    }

    int arow = w * 32 + l15;
    int ko = g * 8;

#pragma unroll
    for (int p = 0; p < 3; ++p) {
        const u16* Wp = p == 0 ? wq : (p == 1 ? wk : wv);
        const float* bp = p == 0 ? qb : (p == 1 ? kb : vb);
        u16* Op = p == 0 ? Qo : (p == 1 ? Ko : Vo);
        const float scale = p == 0 ? 0.125f : 1.0f;

        f32x4 acc[2][8];
#pragma unroll
        for (int nt = 0; nt < 8; ++nt) {
            float bv = bp[nt * 16 + l15];
            acc[0][nt] = (f32x4){bv, bv, bv, bv};
            acc[1][nt] = (f32x4){bv, bv, bv, bv};
        }
#pragma unroll
        for (int kc = 0; kc < 4; ++kc) {
            bf16x8 a0 = *(const bf16x8*)&Xs[arow * XSS + kc * 32 + ko];
            bf16x8 a1 = *(const bf16x8*)&Xs[(arow + 16) * XSS + kc * 32 + ko];
#pragma unroll
            for (int nt = 0; nt < 8; ++nt) {
                bf16x8 b = *(const bf16x8*)(Wp + ((size_t)(nt * 16 + l15) << 7) + kc * 32 + ko);
                acc[0][nt] = MFMA16(a0, b, acc[0][nt], 0, 0, 0);
                acc[1][nt] = MFMA16(a1, b, acc[1][nt], 0, 0, 0);
            }
        }
#pragma unroll
        for (int mt = 0; mt < 2; ++mt) {
#pragma unroll
            for (int r = 0; r < 4; ++r) {
                int ml = g * 4 + r;
#pragma unroll
                for (int nt = 0; nt < 8; ++nt)
                    Ot[w][ml * XSS + nt * 16 + l15] = f2bf(acc[mt][nt][r] * scale);
            }
            asm volatile("s_waitcnt lgkmcnt(0)" ::: "memory");
#pragma unroll
            for (int j = 0; j < 4; ++j) {
                int chunk = j * 64 + lane;
                int rr = chunk >> 4, c16 = chunk & 15;
                bf16x8 v = *(const bf16x8*)&Ot[w][rr * XSS + c16 * 8];
                int grow = row0 + w * 32 + mt * 16 + rr;
                if (grow < M) *(bf16x8*)(Op + (size_t)grow * 128 + c16 * 8) = v;
            }
            asm volatile("s_waitcnt lgkmcnt(0)" ::: "memory");
        }
    }
}

// ---------- fused O-proj + residual + LN1 + FFN1 [round-4 verbatim] ----------
__global__ __launch_bounds__(256) void oproj_ffn1_kernel(const u16* __restrict__ A,
        const u16* __restrict__ Wo, const float* __restrict__ ob,
        const u16* __restrict__ Xres, const float* __restrict__ gma, const float* __restrict__ bta,
        const u16* __restrict__ W1, const float* __restrict__ b1f,
        u16* __restrict__ Xout, u16* __restrict__ F1, int M) {
    __shared__ u16 Xs[128 * XSS];
    __shared__ u16 Ot[4][16 * XSS];
    int tid = threadIdx.x, w = tid >> 6, lane = tid & 63, g = lane >> 4, l15 = lane & 15;
    int row0 = blockIdx.x * 128;
    int rw = row0 + w * 32;
    size_t ar0 = (size_t)min(rw + l15, M - 1) * 128;
    size_t ar1 = (size_t)min(rw + 16 + l15, M - 1) * 128;
    int ko = g * 8;

    f32x4 acc[2][8];
#pragma unroll
    for (int nt = 0; nt < 8; ++nt) {
        float bv = ob[nt * 16 + l15];
        acc[0][nt] = (f32x4){bv, bv, bv, bv};
        acc[1][nt] = (f32x4){bv, bv, bv, bv};
    }
#pragma unroll
    for (int kc = 0; kc < 4; ++kc) {
        bf16x8 a0 = *(const bf16x8*)(A + ar0 + kc * 32 + ko);
        bf16x8 a1 = *(const bf16x8*)(A + ar1 + kc * 32 + ko);
#pragma unroll
        for (int nt = 0; nt < 8; ++nt) {
            bf16x8 b = *(const bf16x8*)(Wo + ((size_t)(nt * 16 + l15) << 7) + kc * 32 + ko);
            acc[0][nt] = MFMA16(a0, b, acc[0][nt], 0, 0, 0);
            acc[1][nt] = MFMA16(a1, b, acc[1][nt], 0, 0, 0);
        }
    }
    float gg[8], bb[8];
#pragma unroll
    for (int nt = 0; nt < 8; ++nt) { gg[nt] = gma[nt * 16 + l15]; bb[nt] = bta[nt * 16 + l15]; }
#pragma unroll
    for (int mt = 0; mt < 2; ++mt) {
#pragma unroll
        for (int r = 0; r < 4; ++r) {
            int rowl = w * 32 + mt * 16 + g * 4 + r;
            size_t rb = (size_t)min(row0 + rowl, M - 1) * 128;
            float v[8];
            float s = 0.f;
#pragma unroll
            for (int nt = 0; nt < 8; ++nt) { v[nt] = acc[mt][nt][r] + bf2f(Xres[rb + nt * 16 + l15]); s += v[nt]; }
            s += __shfl_xor(s, 1); s += __shfl_xor(s, 2); s += __shfl_xor(s, 4); s += __shfl_xor(s, 8);
            float mean = s * 0.0078125f;
            float s2 = 0.f;
#pragma unroll
            for (int nt = 0; nt < 8; ++nt) { float d = v[nt] - mean; s2 += d * d; }
            s2 += __shfl_xor(s2, 1); s2 += __shfl_xor(s2, 2); s2 += __shfl_xor(s2, 4); s2 += __shfl_xor(s2, 8);
            float inv = rsqrtf(s2 * 0.0078125f + 1e-8f);
#pragma unroll
            for (int nt = 0; nt < 8; ++nt)
                Xs[rowl * XSS + nt * 16 + l15] = f2bf((v[nt] - mean) * inv * gg[nt] + bb[nt]);
        }
    }
    __syncthreads();

#pragma unroll
    for (int it = 0; it < 8; ++it) {
        int idx = it * 256 + tid;
        int r = idx >> 4, c8 = idx & 15;
        int grow = row0 + r;
        if (grow < M)
            *(bf16x8*)(Xout + (size_t)grow * 128 + c8 * 8) = *(const bf16x8*)&Xs[r * XSS + c8 * 8];
    }

    int arow = w * 32 + l15;
    f32x4 acc2[2][8];
#pragma unroll
    for (int nt = 0; nt < 8; ++nt) {
        float bv = b1f[nt * 16 + l15];
        acc2[0][nt] = (f32x4){bv, bv, bv, bv};
        acc2[1][nt] = (f32x4){bv, bv, bv, bv};
    }
#pragma unroll
    for (int kc = 0; kc < 4; ++kc) {
        bf16x8 a0 = *(const bf16x8*)&Xs[arow * XSS + kc * 32 + ko];
        bf16x8 a1 = *(const bf16x8*)&Xs[(arow + 16) * XSS + kc * 32 + ko];
#pragma unroll
        for (int nt = 0; nt < 8; ++nt) {
            bf16x8 b = *(const bf16x8*)(W1 + ((size_t)(nt * 16 + l15) << 7) + kc * 32 + ko);
            acc2[0][nt] = MFMA16(a0, b, acc2[0][nt], 0, 0, 0);
            acc2[1][nt] = MFMA16(a1, b, acc2[1][nt], 0, 0, 0);
        }
    }
#pragma unroll
    for (int mt = 0; mt < 2; ++mt) {
#pragma unroll
        for (int r = 0; r < 4; ++r) {
            int ml = g * 4 + r;
#pragma unroll
            for (int nt = 0; nt < 8; ++nt)
                Ot[w][ml * XSS + nt * 16 + l15] = f2bf(fmaxf(acc2[mt][nt][r], 0.f));
        }
        asm volatile("s_waitcnt lgkmcnt(0)" ::: "memory");
#pragma unroll
        for (int j = 0; j < 4; ++j) {
            int chunk = j * 64 + lane;
            int rr = chunk >> 4, c16 = chunk & 15;
            bf16x8 v = *(const bf16x8*)&Ot[w][rr * XSS + c16 * 8];
            int grow = row0 + w * 32 + mt * 16 + rr;
            if (grow < M) *(bf16x8*)(F1 + (size_t)grow * 128 + c16 * 8) = v;
        }
        asm volatile("s_waitcnt lgkmcnt(0)" ::: "memory");
    }
}

// ---------- FFN2 + residual + LN2 (+ final LN + logits when fin) [round-4 verbatim] ----------
__global__ __launch_bounds__(256) void ffn2_ln_kernel(const u16* __restrict__ A,
        const u16* __restrict__ W2, const float* __restrict__ bias,
        const u16* __restrict__ Xres, const float* __restrict__ gma, const float* __restrict__ bta,
        const float* __restrict__ gf, const float* __restrict__ bff, int fin,
        u16* __restrict__ Xout, const float* __restrict__ item,
        const int* __restrict__ pid, const int* __restrict__ nid,
        float* __restrict__ out, int gofs, int M) {
    __shared__ u16 Ot[4][16 * XSS];
    int tid = threadIdx.x, w = tid >> 6, lane = tid & 63, g = lane >> 4, l15 = lane & 15;
    int row0 = blockIdx.x * 128;
    int rw = row0 + w * 32;
    size_t ar0 = (size_t)min(rw + l15, M - 1) * 128;
    size_t ar1 = (size_t)min(rw + 16 + l15, M - 1) * 128;
    int ko = g * 8;

    f32x4 acc[2][8];
#pragma unroll
    for (int nt = 0; nt < 8; ++nt) {
        float bv = bias[nt * 16 + l15];
        acc[0][nt] = (f32x4){bv, bv, bv, bv};
        acc[1][nt] = (f32x4){bv, bv, bv, bv};
    }
#pragma unroll
    for (int kc = 0; kc < 4; ++kc) {
        bf16x8 a0 = *(const bf16x8*)(A + ar0 + kc * 32 + ko);
        bf16x8 a1 = *(const bf16x8*)(A + ar1 + kc * 32 + ko);
#pragma unroll
        for (int nt = 0; nt < 8; ++nt) {
            bf16x8 b = *(const bf16x8*)(W2 + ((size_t)(nt * 16 + l15) << 7) + kc * 32 + ko);
            acc[0][nt] = MFMA16(a0, b, acc[0][nt], 0, 0, 0);
            acc[1][nt] = MFMA16(a1, b, acc[1][nt], 0, 0, 0);
        }
    }
    float gg[8], bb[8], gg2[8], bb2[8];
#pragma unroll
    for (int nt = 0; nt < 8; ++nt) {
        gg[nt] = gma[nt * 16 + l15]; bb[nt] = bta[nt * 16 + l15];
        gg2[nt] = gf[nt * 16 + l15]; bb2[nt] = bff[nt * 16 + l15];
    }
#pragma unroll
    for (int mt = 0; mt < 2; ++mt) {
#pragma unroll
        for (int r = 0; r < 4; ++r) {
            int row = row0 + w * 32 + mt * 16 + g * 4 + r;
            size_t rb = (size_t)min(row, M - 1) * 128;
            float v[8];
            float s = 0.f;
#pragma unroll
            for (int nt = 0; nt < 8; ++nt) { v[nt] = acc[mt][nt][r] + bf2f(Xres[rb + nt * 16 + l15]); s += v[nt]; }
            s += __shfl_xor(s, 1); s += __shfl_xor(s, 2); s += __shfl_xor(s, 4); s += __shfl_xor(s, 8);
            float mean = s * 0.0078125f;
            float s2 = 0.f;
#pragma unroll
            for (int nt = 0; nt < 8; ++nt) { float d = v[nt] - mean; s2 += d * d; }
            s2 += __shfl_xor(s2, 1); s2 += __shfl_xor(s2, 2); s2 += __shfl_xor(s2, 4); s2 += __shfl_xor(s2, 8);
            float inv = rsqrtf(s2 * 0.0078125f + 1e-8f);
#pragma unroll
            for (int nt = 0; nt < 8; ++nt) v[nt] = (v[nt] - mean) * inv * gg[nt] + bb[nt];
            if (fin) {
                float t = 0.f;
#pragma unroll
                for (int nt = 0; nt < 8; ++nt) t += v[nt];
                t += __shfl_xor(t, 1); t += __shfl_xor(t, 2); t += __shfl_xor(t, 4); t += __shfl_xor(t, 8);
                float mean2 = t * 0.0078125f;
                float t2 = 0.f;
#pragma unroll
                for (int nt = 0; nt < 8; ++nt) { float d = v[nt] - mean2; t2 += d * d; }
                t2 += __shfl_xor(t2, 1); t2 += __shfl_xor(t2, 2); t2 += __shfl_xor(t2, 4); t2 += __shfl_xor(t2, 8);
                float inv2 = rsqrtf(t2 * 0.0078125f + 1e-8f);
#pragma unroll
                for (int nt = 0; nt < 8; ++nt) v[nt] = (v[nt] - mean2) * inv2 * gg2[nt] + bb2[nt];
                int gr = gofs + row;
                const float* prow = item + (size_t)pid[gr] * 128;
                const float* nrow = item + (size_t)nid[gr] * 128;
                float sp = 0.f, sn = 0.f;
#pragma unroll
                for (int nt = 0; nt < 8; ++nt) {
                    sp += v[nt] * prow[nt * 16 + l15];
                    sn += v[nt] * nrow[nt * 16 + l15];
                }
                sp += __shfl_xor(sp, 1); sp += __shfl_xor(sp, 2); sp += __shfl_xor(sp, 4); sp += __shfl_xor(sp, 8);
                sn += __shfl_xor(sn, 1); sn += __shfl_xor(sn, 2); sn += __shfl_xor(sn, 4); sn += __shfl_xor(sn, 8);
                if (l15 == 0 && row < M) {
                    out[gr] = sp;
                    out[(size_t)BTOT * L + gr] = sn;
                }
            } else {
                int ml = g * 4 + r;
#pragma unroll
                for (int nt = 0; nt < 8; ++nt)
                    Ot[w][ml * XSS + nt * 16 + l15] = f2bf(v[nt]);
            }
        }
        if (!fin) {
            asm volatile("s_waitcnt lgkmcnt(0)" ::: "memory");
#pragma unroll
            for (int j = 0; j < 4; ++j) {
                int chunk = j * 64 + lane;
                int rr = chunk >> 4, c16 = chunk & 15;
                bf16x8 v = *(const bf16x8*)&Ot[w][rr * XSS + c16 * 8];
                int grow = row0 + w * 32 + mt * 16 + rr;
                if (grow < M) *(bf16x8*)(Xout + (size_t)grow * 128 + c16 * 8) = v;
            }
            asm volatile("s_waitcnt lgkmcnt(0)" ::: "memory");
        }
    }
}

// ---------- bf16 MFMA flash attention [round-15 verbatim, launch_bounds (256,2)] ----------
__global__ __launch_bounds__(256, 2) void attn_mfma_kernel(u16* __restrict__ Q,
                                                           const u16* __restrict__ K,
                                                           const u16* __restrict__ V) {
    __shared__ u16 lds_s[64 * 264];
    int b = blockIdx.x >> 1;
    int h = blockIdx.x & 1;
    int tid = threadIdx.x;
    int w = tid >> 6;
    int lane = tid & 63;
    int g = lane >> 4;
    int l15 = lane & 15;

    const u16* Kb = K + ((size_t)b * L) * H + h * HD;
    const u16* Vb = V + ((size_t)b * L) * H + h * HD;
    u16* Qb = Q + ((size_t)b * L) * H + h * HD;

    {
        int d = tid & 63;
        int kq = tid >> 6;
#pragma unroll 8
        for (int it = 0; it < 64; ++it) {
            int k = it * 4 + kq;
            lds_s[d * 264 + k] = Vb[(size_t)min(k, L - 1) * H + d];
        }
    }

    bf16x8 qf[4][2];
    int qrow[4];
#pragma unroll
    for (int nt = 0; nt < 4; ++nt) {
        int q = nt * 64 + w * 16 + l15;
        qrow[nt] = q;
        const u16* src = Qb + (size_t)min(q, L - 1) * H;
        qf[nt][0] = *(const bf16x8*)(src + g * 8);
        qf[nt][1] = *(const bf16x8*)(src + 32 + g * 8);
    }
    __syncthreads();

    f32x4 o[4][4];
    float mrun[4], lrun[4];
#pragma unroll
    for (int i = 0; i < 4; ++i) {
        mrun[i] = -1e30f; lrun[i] = 0.f;
#pragma unroll
        for (int j = 0; j < 4; ++j) o[i][j] = (f32x4){0.f, 0.f, 0.f, 0.f};
    }

    int rp = 8 * (l15 >> 2) + (l15 & 3);
    const f32x4 czero = {0.f, 0.f, 0.f, 0.f};

#pragma unroll
    for (int kc = 0; kc < 4; ++kc) {
        int kbase = kc * 64;
        bf16x8 ka[4][2];
#pragma unroll
        for (int mt = 0; mt < 4; ++mt) {
            int krow = kbase + (mt >> 1) * 32 + (mt & 1) * 4 + rp;
            const u16* src = Kb + (size_t)min(krow, L - 1) * H;
            ka[mt][0] = *(const bf16x8*)(src + g * 8);
            ka[mt][1] = *(const bf16x8*)(src + 32 + g * 8);
        }
#pragma unroll
        for (int nt = 0; nt < 4; ++nt) {
            if (nt < kc) continue;
            int q = qrow[nt];
            f32x4 c[4];
#pragma unroll
            for (int mt = 0; mt < 4; ++mt) {
                c[mt] = MFMA16(ka[mt][0], qf[nt][0], czero, 0, 0, 0);
                c[mt] = MFMA16(ka[mt][1], qf[nt][1], c[mt], 0, 0, 0);
            }
            float pm = -1e30f;
#pragma unroll
            for (int mt = 0; mt < 4; ++mt) {
#pragma unroll
                for (int r = 0; r < 4; ++r) {
                    int kact = kbase + 32 * (mt >> 1) + 4 * (mt & 1) + 8 * g + r;
                    float s = (kact <= q) ? c[mt][r] : -1e30f;
                    c[mt][r] = s;
                    pm = fmaxf(pm, s);
                }
            }
            pm = fmaxf(pm, __shfl_xor(pm, 16));
            pm = fmaxf(pm, __shfl_xor(pm, 32));
            float mnew = fmaxf(mrun[nt], pm);
            float sf = __expf(mrun[nt] - mnew);
            mrun[nt] = mnew;
            float ps = 0.f;
#pragma unroll
            for (int mt = 0; mt < 4; ++mt) {
#pragma unroll
                for (int r = 0; r < 4; ++r) {
                    float p = __expf(c[mt][r] - mnew);
                    c[mt][r] = p;
                    ps += p;
                }
            }
            ps += __shfl_xor(ps, 16);
            ps += __shfl_xor(ps, 32);
            lrun[nt] = lrun[nt] * sf + ps;
#pragma unroll
            for (int md = 0; md < 4; ++md) {
#pragma unroll
                for (int r = 0; r < 4; ++r) o[md][nt][r] *= sf;
            }
#pragma unroll
            for (int ks = 0; ks < 2; ++ks) {
                bf16x8 pb;
#pragma unroll
                for (int j = 0; j < 8; ++j)
                    pb[j] = (short)f2bf(c[2 * ks + (j >> 2)][j & 3]);
#pragma unroll
                for (int md = 0; md < 4; ++md) {
                    const u16* vp = &lds_s[(md * 16 + l15) * 264 + kbase + ks * 32 + g * 8];
                    bf16x8 va = *(const bf16x8*)vp;
                    o[md][nt] = MFMA16(va, pb, o[md][nt], 0, 0, 0);
                }
            }
        }
    }

    __syncthreads();
    u16* Ot = lds_s;
#pragma unroll
    for (int nt = 0; nt < 4; ++nt) {
        float inv = 1.0f / lrun[nt];
        int q = qrow[nt];
        int sw = (q & 7) << 3;
#pragma unroll
        for (int md = 0; md < 4; ++md) {
            int d0 = md * 16 + g * 4;
            unsigned p0 = (unsigned)f2bf(o[md][nt][0] * inv) | ((unsigned)f2bf(o[md][nt][1] * inv) << 16);
            unsigned p1 = (unsigned)f2bf(o[md][nt][2] * inv) | ((unsigned)f2bf(o[md][nt][3] * inv) << 16);
            uint2 u; u.x = p0; u.y = p1;
            *(uint2*)&Ot[q * 64 + (d0 ^ sw)] = u;
        }
    }
    __syncthreads();
    {
        int d = tid & 63;
        for (int q = tid >> 6; q < L; q += 4)
            Qb[(size_t)q * H + d] = Ot[q * 64 + (d ^ ((q & 7) << 3))];
    }
}

extern "C" void kernel_launch(void* const* d_in, const int* in_sizes, int n_in,
                              void* d_out, int out_size, void* d_ws, size_t ws_size,
                              hipStream_t stream) {
    const int* log_seqs = (const int*)d_in[1];
    const int* pos_seqs = (const int*)d_in[2];
    const int* neg_seqs = (const int*)d_in[3];
    const float* item = (const float*)d_in[4];
    const float* post = (const float*)d_in[5];
    const float* qw = (const float*)d_in[6];
    const float* kw = (const float*)d_in[7];
    const float* vw = (const float*)d_in[8];
    const float* ow = (const float*)d_in[9];
    const float* qb = (const float*)d_in[10];
    const float* kb = (const float*)d_in[11];
    const float* vb = (const float*)d_in[12];
    const float* ob = (const float*)d_in[13];
    const float* w1 = (const float*)d_in[14];
    const float* b1 = (const float*)d_in[15];
    const float* w2 = (const float*)d_in[16];
    const float* b2 = (const float*)d_in[17];
    const float* ln1g = (const float*)d_in[18];
    const float* ln1b = (const float*)d_in[19];
    const float* ln2g = (const float*)d_in[20];
    const float* ln2b = (const float*)d_in[21];
    const float* lnfg = (const float*)d_in[22];
    const float* lnfb = (const float*)d_in[23];
    float* out = (float*)d_out;

    // single chunk: 14 dispatches total (embed fused into layer-0 qkv)
    int cb = BTOT;
    while (cb > 8 && (size_t)cb * L * H * 8 + 12 * HH * 2 > ws_size) cb >>= 1;
    size_t nbe = (size_t)cb * L * H;
    u16* X16 = (u16*)d_ws;
    u16* Q16 = X16 + nbe;
    u16* K16 = Q16 + nbe;
    u16* V16 = K16 + nbe;
    u16* w16 = V16 + nbe;

    const float* wsrc[6] = {qw, kw, vw, ow, w1, w2};
    int n8 = NB * HH / 8;
    for (int t = 0; t < 6; ++t)
        cvt_kernel<<<(n8 + 255) / 256, 256, 0, stream>>>(wsrc[t], w16 + (size_t)t * NB * HH, n8);

    for (int b0 = 0; b0 < BTOT; b0 += cb) {
        int M = cb * L;
        int gblk = (M + 127) / 128;
        for (int i = 0; i < NB; ++i) {
            size_t wo = (size_t)i * HH;
            int bofs = i * H;
            qkv_kernel<<<gblk, 256, 0, stream>>>(X16,
                    (i == 0) ? (log_seqs + (size_t)b0 * L) : nullptr,
                    (const float4*)item, (const float4*)post, X16,
                    w16 + 0 * NB * HH + wo, w16 + 1 * NB * HH + wo, w16 + 2 * NB * HH + wo,
                    qb + bofs, kb + bofs, vb + bofs, Q16, K16, V16, M);
            attn_mfma_kernel<<<cb * 2, 256, 0, stream>>>(Q16, K16, V16);
            oproj_ffn1_kernel<<<gblk, 256, 0, stream>>>(Q16, w16 + 3 * NB * HH + wo, ob + bofs,
                    X16, ln1g + bofs, ln1b + bofs,
                    w16 + 4 * NB * HH + wo, b1 + bofs, X16, K16, M);
            ffn2_ln_kernel<<<gblk, 256, 0, stream>>>(K16, w16 + 5 * NB * HH + wo, b2 + bofs,
                    X16, ln2g + bofs, ln2b + bofs, lnfg, lnfb, (i == NB - 1) ? 1 : 0,
                    X16, item, pos_seqs, neg_seqs, out, b0 * L, M);
        }
    }
}